// Round 11
// baseline (207.455 us; speedup 1.0000x reference)
//
#include <hip/hip_runtime.h>
#include <stdint.h>
#include <math.h>

typedef __bf16 bf16_t;
typedef __attribute__((ext_vector_type(8))) __bf16 bf16x8;
typedef __attribute__((ext_vector_type(4))) __bf16 bf16x4;
typedef __attribute__((ext_vector_type(4))) float f32x4;

#define N_TOK 4096
#define D_MODEL 1024
#define HEADS 16
#define DH 64
// Softmax scale folded into Q's fused L2-normalize (gemm epilogue): Q' = C1 * Q/||Q||
// so S^T already = C1*dot and p = exp2(S^T). The old -C2 shift is a constant factor
// on every p in a row and cancels in the final l-division.
#define C1 11.541560327111707f   // 8 * log2(e)

// async global->LDS 16B copy (dest = wave-uniform base + lane*16)
__device__ __forceinline__ void async_copy16(const void* g, void* l) {
    __builtin_amdgcn_global_load_lds(
        (const __attribute__((address_space(1))) unsigned int*)g,
        (__attribute__((address_space(3))) unsigned int*)l, 16, 0, 0);
}

// ------- fused prep: cast x -> bf16 (blocks 0..4095) + transpose W (4096..5119) ----
__global__ __launch_bounds__(256) void prep_kernel(
    const float* __restrict__ x, bf16_t* __restrict__ xb,
    const float* __restrict__ W0, const float* __restrict__ W1,
    const float* __restrict__ W2, const float* __restrict__ W3,
    bf16_t* __restrict__ T0, bf16_t* __restrict__ T1,
    bf16_t* __restrict__ T2, bf16_t* __restrict__ T3) {
    __shared__ bf16_t t[64][72];
    const int b = blockIdx.x;
    if (b < 4096) {                       // ---- cast x ----
        int i = (b * 256 + threadIdx.x) * 4;
        float4 v = *(const float4*)(x + i);
        bf16x4 o;
        o[0] = (bf16_t)v.x; o[1] = (bf16_t)v.y; o[2] = (bf16_t)v.z; o[3] = (bf16_t)v.w;
        *(bf16x4*)(xb + i) = o;
        return;
    }
    const int idx = b - 4096;             // ---- transpose+cast one 64x64 W tile ----
    const int z = idx >> 8;               // matrix 0..3
    const int rem = idx & 255;
    const int k0 = (rem & 15) * 64, n0 = (rem >> 4) * 64;
    const float* W; bf16_t* T;
    switch (z) {
        case 0: W = W0; T = T0; break;
        case 1: W = W1; T = T1; break;
        case 2: W = W2; T = T2; break;
        default: W = W3; T = T3; break;
    }
    int tx = threadIdx.x & 63, ty = threadIdx.x >> 6;
#pragma unroll
    for (int i = 0; i < 16; i++) {
        int kl = ty * 16 + i;
        t[kl][tx] = (bf16_t)W[(size_t)(k0 + kl) * D_MODEL + n0 + tx];
    }
    __syncthreads();
#pragma unroll
    for (int i = 0; i < 16; i++) {
        int nl = ty * 16 + i;
        T[(size_t)(n0 + nl) * D_MODEL + k0 + tx] = t[tx][nl];
    }
}

// ------- 128x128 MFMA GEMM, v16 staging + XCD-pinned B-panels ----------------------
// 1-D grid; xcd = b&7 (round-robin dispatch); each XCD owns npx consecutive n-tiles
// so its B-panels (npx x 256KB) stay hot in the private 4MB L2 across all M-blocks.
// Old 2-D grid streamed ALL of B through EVERY XCD's L2 (~390MB L3 traffic/GEMM).
// preload tile0; per step: ONE barrier, prefetch k+1 into other buf, compute k.
// C[M][ldc] tile = A[M][1024] * Bt[N][1024]^T ; optional fused L2-norm per 64-col head
// Q columns (n0<1024) additionally scaled by C1 = 8*log2(e) (softmax scale folding).
template <int WRITE_F32, int NORM>
__global__ __launch_bounds__(256) void gemm_tile(const bf16_t* __restrict__ A,
                                                 const bf16_t* __restrict__ Bt,
                                                 void* __restrict__ Cout, int ldc,
                                                 int npx, int mtiles) {
    constexpr int K = D_MODEL;
    __shared__ __align__(16) bf16_t As[2][128 * 32];
    __shared__ __align__(16) bf16_t Bs[2][128 * 32];
    const int tid = threadIdx.x;
    const int bid = blockIdx.x;
    const int idx = bid >> 3;
    const int nt = (bid & 7) * npx + idx / mtiles;
    const int mt = idx % mtiles;
    const int m0 = mt * 128;
    const int n0 = nt * 128;
    const int wave = tid >> 6;
    const int lane = tid & 63;
    const int l15 = lane & 15;
    const int quad = lane >> 4;
    const int wm = (wave >> 1) * 64;
    const int wn = (wave & 1) * 64;
    f32x4 acc[4][4] = {};

    // staging: thread t handles chunks t and t+256; chunk c: row=c>>2, off=(c&3)*8
    const int srow = tid >> 2;
    const int soff = (tid & 3) * 8;
    const bf16_t* gA = A + (size_t)(m0 + srow) * K + soff;
    const bf16_t* gB = Bt + (size_t)(n0 + srow) * K + soff;
    constexpr int HGAP = 64 * K;

    // preload K-tile 0 into buf 0
    async_copy16(gA, &As[0][tid * 8]);
    async_copy16(gA + HGAP, &As[0][tid * 8 + 2048]);
    async_copy16(gB, &Bs[0][tid * 8]);
    async_copy16(gB + HGAP, &Bs[0][tid * 8 + 2048]);

    for (int kt = 0; kt < K; kt += 32) {
        const int b = (kt >> 5) & 1;
        __syncthreads();               // drains vmcnt: tile kt (buf b) landed; prior readers done
        if (kt + 32 < K) {             // prefetch tile kt+32 into the other buffer
            async_copy16(gA + kt + 32, &As[b ^ 1][tid * 8]);
            async_copy16(gA + HGAP + kt + 32, &As[b ^ 1][tid * 8 + 2048]);
            async_copy16(gB + kt + 32, &Bs[b ^ 1][tid * 8]);
            async_copy16(gB + HGAP + kt + 32, &Bs[b ^ 1][tid * 8 + 2048]);
        }
        bf16x8 af[4], bfr[4];
#pragma unroll
        for (int mi = 0; mi < 4; mi++)
            af[mi] = *(const bf16x8*)(&As[b][(wm + mi * 16 + l15) * 32 + quad * 8]);
#pragma unroll
        for (int ni = 0; ni < 4; ni++)
            bfr[ni] = *(const bf16x8*)(&Bs[b][(wn + ni * 16 + l15) * 32 + quad * 8]);
#pragma unroll
        for (int mi = 0; mi < 4; mi++)
#pragma unroll
            for (int ni = 0; ni < 4; ni++)
                acc[mi][ni] = __builtin_amdgcn_mfma_f32_16x16x32_bf16(
                    af[mi], bfr[ni], acc[mi][ni], 0, 0, 0);
    }

    if (NORM && n0 < 2048) {   // wave's 64-col span == one head: fused F.normalize
        const float post = (n0 < 1024) ? C1 : 1.0f;   // fold softmax scale into Q
#pragma unroll
        for (int mi = 0; mi < 4; mi++)
#pragma unroll
            for (int r = 0; r < 4; r++) {
                float s = 0.f;
#pragma unroll
                for (int ni = 0; ni < 4; ni++) {
                    float v = acc[mi][ni][r];
                    s += v * v;
                }
                s += __shfl_xor(s, 1);
                s += __shfl_xor(s, 2);
                s += __shfl_xor(s, 4);
                s += __shfl_xor(s, 8);
                float sc = post / fmaxf(sqrtf(s), 1e-12f);
#pragma unroll
                for (int ni = 0; ni < 4; ni++) acc[mi][ni][r] *= sc;
            }
    }
#pragma unroll
    for (int mi = 0; mi < 4; mi++)
#pragma unroll
        for (int ni = 0; ni < 4; ni++)
#pragma unroll
            for (int r = 0; r < 4; r++) {
                int row = m0 + wm + mi * 16 + quad * 4 + r;
                int col = n0 + wn + ni * 16 + l15;
                float v = acc[mi][ni][r];
                if (WRITE_F32)
                    ((float*)Cout)[(size_t)row * ldc + col] = v;
                else
                    ((bf16_t*)Cout)[(size_t)row * ldc + col] = (bf16_t)v;
            }
}

// ------- 64x128 MFMA GEMM (O-proj), XCD-pinned: nt = b&7 -> ONE B-panel per XCD ----
// 512 blocks = 2/CU; B-panel (128 cols x 1024 K = 256KB) stays hot in its XCD L2
// across all 64 M-blocks. dbuf kept; 24KB LDS.
__global__ __launch_bounds__(256) void gemm_o64(const bf16_t* __restrict__ A,
                                                const bf16_t* __restrict__ Bt,
                                                float* __restrict__ Cout) {
    constexpr int K = D_MODEL;
    __shared__ __align__(16) bf16_t As[2][64 * 32];
    __shared__ __align__(16) bf16_t Bs[2][128 * 32];
    const int tid = threadIdx.x;
    const int bid = blockIdx.x;
    const int m0 = (bid >> 3) * 64;
    const int n0 = (bid & 7) * 128;
    const int wave = tid >> 6;
    const int lane = tid & 63;
    const int l15 = lane & 15;
    const int quad = lane >> 4;
    const int wm = (wave >> 1) * 32;
    const int wn = (wave & 1) * 64;
    f32x4 acc[2][4] = {};

    // staging: A chunk tid -> (row=tid>>2, off=(tid&3)*8); B chunks tid, tid+256
    const int srow = tid >> 2;
    const int soff = (tid & 3) * 8;
    const bf16_t* gA = A + (size_t)(m0 + srow) * K + soff;
    const bf16_t* gB = Bt + (size_t)(n0 + srow) * K + soff;
    constexpr int HGAP = 64 * K;

    // preload K-tile 0 into buf 0
    async_copy16(gA, &As[0][tid * 8]);
    async_copy16(gB, &Bs[0][tid * 8]);
    async_copy16(gB + HGAP, &Bs[0][tid * 8 + 2048]);

    for (int kt = 0; kt < K; kt += 32) {
        const int b = (kt >> 5) & 1;
        __syncthreads();               // tile kt (buf b) landed; prior readers done
        if (kt + 32 < K) {             // prefetch tile kt+32 into the other buffer
            async_copy16(gA + kt + 32, &As[b ^ 1][tid * 8]);
            async_copy16(gB + kt + 32, &Bs[b ^ 1][tid * 8]);
            async_copy16(gB + HGAP + kt + 32, &Bs[b ^ 1][tid * 8 + 2048]);
        }
        bf16x8 af[2], bfr[4];
#pragma unroll
        for (int mi = 0; mi < 2; mi++)
            af[mi] = *(const bf16x8*)(&As[b][(wm + mi * 16 + l15) * 32 + quad * 8]);
#pragma unroll
        for (int ni = 0; ni < 4; ni++)
            bfr[ni] = *(const bf16x8*)(&Bs[b][(wn + ni * 16 + l15) * 32 + quad * 8]);
#pragma unroll
        for (int mi = 0; mi < 2; mi++)
#pragma unroll
            for (int ni = 0; ni < 4; ni++)
                acc[mi][ni] = __builtin_amdgcn_mfma_f32_16x16x32_bf16(
                    af[mi], bfr[ni], acc[mi][ni], 0, 0, 0);
    }

#pragma unroll
    for (int mi = 0; mi < 2; mi++)
#pragma unroll
        for (int ni = 0; ni < 4; ni++)
#pragma unroll
            for (int r = 0; r < 4; r++) {
                int row = m0 + wm + mi * 16 + quad * 4 + r;
                int col = n0 + wn + ni * 16 + l15;
                Cout[(size_t)row * D_MODEL + col] = acc[mi][ni][r];
            }
}

// ---- V (QKV cols 2048..3071) -> Vt[h][d][n], tokens in MFMA k-enum order ----------
// Within each 32-token tile, position kk holds token j(kk) = 16*((kk&7)>>2)
// + 4*(kk>>3) + (kk&3)  => PV A-fragment becomes ONE contiguous b128 LDS read.
__global__ __launch_bounds__(256) void transpose_v_kernel(const bf16_t* __restrict__ QKV,
                                                          bf16_t* __restrict__ Vt) {
    __shared__ bf16_t t[64][72];
    int n0 = blockIdx.x * 64;
    int h = blockIdx.y;
    int tx = threadIdx.x & 63, ty = threadIdx.x >> 6;
#pragma unroll
    for (int i = 0; i < 16; i++) {
        int nl = ty * 16 + i;
        t[nl][tx] = QKV[(size_t)(n0 + nl) * 3072 + 2048 + h * DH + tx];
    }
    __syncthreads();
    const int e = tx & 7, q = (tx >> 3) & 3;
    const int J = (tx & 32) + 16 * (e >> 2) + 4 * q + (e & 3);   // permuted token
#pragma unroll
    for (int i = 0; i < 16; i++) {
        int dl = ty * 16 + i;
        Vt[(size_t)(h * DH + dl) * N_TOK + n0 + tx] = t[J][dl];
    }
}

// ---------------- flash attention v14 (final): v12 + softmax VALU cuts -------------
// Nine rounds of structural probes (v11/v13/v15/v17/v18/v19) all lost 28-110%:
// every deviation from this flat identical-work-per-wave loop inflates VALU/address
// work more than it saves on the targeted resource. This body compiles to 68 VGPR
// and is the accepted local optimum: 16 rows/wave, balanced (63-u, u) pairing,
// dbuf, 1 barrier/64-token tile, softmax scale folded into Q, l via ones-MFMA.
__global__ __launch_bounds__(256) void attn_kernel(const bf16_t* __restrict__ QKV,
                                                   const bf16_t* __restrict__ Vt,
                                                   bf16_t* __restrict__ O) {
    __shared__ __align__(16) bf16_t Ks[2][4096];      // [buf][64 j x 64 d] chunk c@row = src c^(row&7)
    __shared__ __align__(16) bf16_t Vs[2][2][2048];   // [buf][half][64 d x 32 kk] chunk c@row d = src c^((d>>1)&3)
    const int tid = threadIdx.x;
    const int wave = tid >> 6;
    const int lane = tid & 63;
    const int l15 = lane & 15;
    const int quad = lane >> 4;

    const int xcd = blockIdx.x & 7;
    const int t = blockIdx.x >> 3;          // 0..63
    const int h = xcd * 2 + (t & 1);        // 2 heads per XCD
    const int u = t >> 1;                   // 0..31: pair (63-u, u)

    const bf16_t* Qb = QKV + h * DH;
    const bf16_t* Kb = QKV + 1024 + h * DH;
    const bf16_t* Vb = Vt + (size_t)h * DH * N_TOK;

    // staging: K chunk idx L=tid+256*i -> (row=(tid>>3)+32*i, c=tid&7), src c^(row&7)
    const int krow = tid >> 3;
    const int kc = (tid & 7) ^ (krow & 7);
    const bf16_t* gK = Kb + (size_t)krow * 3072 + kc * 8;
    // V chunk idx tid -> (d=tid>>2, c=tid&3), src chunk c^((d>>1)&3); two 32-kk halves
    const int vd = tid >> 2;
    const int vc = (tid & 3) ^ ((vd >> 1) & 3);
    const bf16_t* gV = Vb + (size_t)vd * N_TOK + vc * 8;

    const int ksw = l15 & 7;             // K-tile read swizzle
    const int vsw = (l15 >> 1) & 3;      // V-tile read swizzle (16B chunks)

    // all-ones A-fragment for MFMA row-sums of P
    bf16x8 vone;
#pragma unroll
    for (int i = 0; i < 8; i++) vone[i] = (bf16_t)1.0f;

    for (int ph = 0; ph < 2; ph++) {
        const int g = ph ? u : 63 - u;       // heavy first, then light
        const int i0 = g * 64 + wave * 16;   // this wave's 16 rows

        // Q^T B-fragment: lane n=l15 -> row i0+l15, k=quad*8.. contiguous
        bf16x8 aq[2];
#pragma unroll
        for (int kd = 0; kd < 2; kd++)
            aq[kd] = *(const bf16x8*)(Qb + (size_t)(i0 + l15) * 3072 + kd * 32 + quad * 8);

        f32x4 od[4] = {};          // O^T[d=mt*16+quad*4+r][i=l15]
        f32x4 lv = {};             // ones-MFMA row-sum accumulator (all rows equal)

        if (ph) __syncthreads();   // phase-0 readers done before buf0 overwrite
        // preload tile 0 into buf 0
        async_copy16(gK, &Ks[0][tid * 8]);
        async_copy16(gK + (size_t)32 * 3072, &Ks[0][tid * 8 + 2048]);
        async_copy16(gV, &Vs[0][0][tid * 8]);
        async_copy16(gV + 32, &Vs[0][1][tid * 8]);

        for (int jt = 0; jt <= g; jt++) {
            __syncthreads();                 // drains vmcnt: buf[jt&1] ready; prior reads done
            if (jt < g) {                    // prefetch next tile into other buf
                const int b = (jt + 1) & 1;
                const bf16_t* kn = gK + (size_t)(jt + 1) * 64 * 3072;
                async_copy16(kn, &Ks[b][tid * 8]);
                async_copy16(kn + (size_t)32 * 3072, &Ks[b][tid * 8 + 2048]);
                async_copy16(gV + (jt + 1) * 64, &Vs[b][0][tid * 8]);
                async_copy16(gV + (jt + 1) * 64 + 32, &Vs[b][1][tid * 8]);
            }
            const bf16_t* KS = Ks[jt & 1];
            const bool diag = (jt == g);
            const int jh_max = diag ? wave : 3;

            // ---- S^T = K.Q^T over 4 jh sub-tiles (independent chains) ----
            bf16x8 ak[4][2];
#pragma unroll
            for (int jh = 0; jh < 4; jh++) {
                if (jh > jh_max) continue;
#pragma unroll
                for (int kd = 0; kd < 2; kd++)
                    ak[jh][kd] = *(const bf16x8*)(&KS[(jh * 16 + l15) * 64 +
                                                      (((kd * 4 + quad) ^ ksw) * 8)]);
            }
            f32x4 sj[4] = {};
#pragma unroll
            for (int kd = 0; kd < 2; kd++)
#pragma unroll
                for (int jh = 0; jh < 4; jh++) {
                    if (jh > jh_max) continue;
                    sj[jh] = __builtin_amdgcn_mfma_f32_16x16x32_bf16(ak[jh][kd], aq[kd], sj[jh], 0, 0, 0);
                }

            // ---- softmax: p = exp2(sj) (scale pre-folded into Q, shift cancels) ----
            float p[4][4] = {};
#pragma unroll
            for (int jh = 0; jh < 4; jh++) {
                if (jh > jh_max) continue;
                if (diag && jh == wave) {
#pragma unroll
                    for (int r = 0; r < 4; r++)
                        p[jh][r] = (quad * 4 + r > l15) ? 0.f
                                   : __builtin_amdgcn_exp2f(sj[jh][r]);
                } else {
#pragma unroll
                    for (int r = 0; r < 4; r++)
                        p[jh][r] = __builtin_amdgcn_exp2f(sj[jh][r]);
                }
            }
            // pack P^T B-fragments: half H covers jh = 2H, 2H+1 (k-enum j(q,e))
            bf16x8 pk8[2];
#pragma unroll
            for (int H = 0; H < 2; H++)
#pragma unroll
                for (int r = 0; r < 4; r++) {
                    pk8[H][r] = (bf16_t)p[2 * H][r];
                    pk8[H][4 + r] = (bf16_t)p[2 * H + 1][r];
                }

            // ---- l += ones.P^T (row-sums via matrix pipe; all output rows equal) ----
            lv = __builtin_amdgcn_mfma_f32_16x16x32_bf16(vone, pk8[0], lv, 0, 0, 0);
            if (jh_max >= 2)
                lv = __builtin_amdgcn_mfma_f32_16x16x32_bf16(vone, pk8[1], lv, 0, 0, 0);

            // ---- O^T += V^T.P^T : one b128 A-frag per (mt, half) ----
            const bf16_t* VS0 = Vs[jt & 1][0];
#pragma unroll
            for (int mt = 0; mt < 4; mt++) {
                bf16x8 vf = *(const bf16x8*)(&VS0[(mt * 16 + l15) * 32 + ((quad ^ vsw) * 8)]);
                od[mt] = __builtin_amdgcn_mfma_f32_16x16x32_bf16(vf, pk8[0], od[mt], 0, 0, 0);
            }
            if (jh_max >= 2) {
                const bf16_t* VS1 = Vs[jt & 1][1];
#pragma unroll
                for (int mt = 0; mt < 4; mt++) {
                    bf16x8 vf = *(const bf16x8*)(&VS1[(mt * 16 + l15) * 32 + ((quad ^ vsw) * 8)]);
                    od[mt] = __builtin_amdgcn_mfma_f32_16x16x32_bf16(vf, pk8[1], od[mt], 0, 0, 0);
                }
            }
        }

        // ---- normalize: lv[r] = full row-sum for col i=l15 (contraction spans lanes) ----
        float inv = 1.0f / lv[0];

#pragma unroll
        for (int mt = 0; mt < 4; mt++) {
            bf16x4 o;
#pragma unroll
            for (int r = 0; r < 4; r++) o[r] = (bf16_t)(od[mt][r] * inv);
            *(bf16x4*)(&O[(size_t)(i0 + l15) * D_MODEL + h * DH + mt * 16 + quad * 4]) = o;
        }
    }
}

extern "C" void kernel_launch(void* const* d_in, const int* in_sizes, int n_in,
                              void* d_out, int out_size, void* d_ws, size_t ws_size,
                              hipStream_t stream) {
    const float* x  = (const float*)d_in[0];
    const float* Wq = (const float*)d_in[1];
    const float* Wk = (const float*)d_in[2];
    const float* Wv = (const float*)d_in[3];
    const float* Wo = (const float*)d_in[4];
    float* out = (float*)d_out;
    char* ws = (char*)d_ws;
    const size_t MB = 1024 * 1024;
    bf16_t* xb   = (bf16_t*)(ws);             // 8 MB
    bf16_t* Wt3  = (bf16_t*)(ws + 8 * MB);    // 6 MB  [3072][1024] q|k|v
    bf16_t* Wot  = (bf16_t*)(ws + 14 * MB);   // 2 MB
    bf16_t* QKV  = (bf16_t*)(ws + 16 * MB);   // 24 MB [4096][3072]
    bf16_t* Vt   = (bf16_t*)(ws + 40 * MB);   // 8 MB  [16][64][4096] (k-enum order)
    bf16_t* Ob   = (bf16_t*)(ws + 48 * MB);   // 8 MB  -> ends at 56 MB

    prep_kernel<<<5120, 256, 0, stream>>>(x, xb, Wq, Wk, Wv, Wo,
                                          Wt3, Wt3 + 1024 * 1024, Wt3 + 2 * 1024 * 1024, Wot);
    // QKV: 768 blocks; 8 XCDs x 3 n-tiles x 32 m-tiles (bijective: 768 % 8 == 0)
    gemm_tile<0, 1><<<768, 256, 0, stream>>>(xb, Wt3, QKV, 3072, 3, 32);
    dim3 gv(N_TOK / 64, HEADS);
    transpose_v_kernel<<<gv, 256, 0, stream>>>(QKV, Vt);
    attn_kernel<<<512, 256, 0, stream>>>(QKV, Vt, Ob);
    // O-proj: 512 blocks; 8 XCDs x 1 n-tile x 64 m-tiles
    gemm_o64<<<512, 256, 0, stream>>>(Ob, Wot, out);
}

// Round 12
// 200.572 us; speedup vs baseline: 1.0343x; 1.0343x over previous
//
#include <hip/hip_runtime.h>
#include <stdint.h>
#include <math.h>

typedef __bf16 bf16_t;
typedef __attribute__((ext_vector_type(8))) __bf16 bf16x8;
typedef __attribute__((ext_vector_type(4))) __bf16 bf16x4;
typedef __attribute__((ext_vector_type(4))) float f32x4;

#define N_TOK 4096
#define D_MODEL 1024
#define HEADS 16
#define DH 64
// Softmax scale folded into Q's fused L2-normalize (gemm epilogue): Q' = C1 * Q/||Q||
// so S^T already = C1*dot and p = exp2(S^T). The old -C2 shift is a constant factor
// on every p in a row and cancels in the final l-division.
#define C1 11.541560327111707f   // 8 * log2(e)

// async global->LDS 16B copy (dest = wave-uniform base + lane*16)
__device__ __forceinline__ void async_copy16(const void* g, void* l) {
    __builtin_amdgcn_global_load_lds(
        (const __attribute__((address_space(1))) unsigned int*)g,
        (__attribute__((address_space(3))) unsigned int*)l, 16, 0, 0);
}

// ---------------- cast x -> bf16 ----------------
__global__ __launch_bounds__(256) void cast_x_kernel(const float* __restrict__ x,
                                                     bf16_t* __restrict__ xb) {
    int i = (blockIdx.x * 256 + threadIdx.x) * 4;
    float4 v = *(const float4*)(x + i);
    bf16x4 o;
    o[0] = (bf16_t)v.x; o[1] = (bf16_t)v.y; o[2] = (bf16_t)v.z; o[3] = (bf16_t)v.w;
    *(bf16x4*)(xb + i) = o;
}

// ------- transpose + cast W[k][n] -> Wt[n][k] bf16 (q,k,v into one 3072-row buf) ----
__global__ __launch_bounds__(256) void transpose_w_kernel(
    const float* __restrict__ W0, const float* __restrict__ W1,
    const float* __restrict__ W2, const float* __restrict__ W3,
    bf16_t* __restrict__ T0, bf16_t* __restrict__ T1,
    bf16_t* __restrict__ T2, bf16_t* __restrict__ T3) {
    __shared__ bf16_t t[64][72];
    const float* W; bf16_t* T;
    switch (blockIdx.z) {
        case 0: W = W0; T = T0; break;
        case 1: W = W1; T = T1; break;
        case 2: W = W2; T = T2; break;
        default: W = W3; T = T3; break;
    }
    int k0 = blockIdx.x * 64, n0 = blockIdx.y * 64;
    int tx = threadIdx.x & 63, ty = threadIdx.x >> 6;
#pragma unroll
    for (int i = 0; i < 16; i++) {
        int kl = ty * 16 + i;
        t[kl][tx] = (bf16_t)W[(size_t)(k0 + kl) * D_MODEL + n0 + tx];
    }
    __syncthreads();
#pragma unroll
    for (int i = 0; i < 16; i++) {
        int nl = ty * 16 + i;
        T[(size_t)(n0 + nl) * D_MODEL + k0 + tx] = t[tx][nl];
    }
}

// ------- 128x128 MFMA GEMM, v16: TRUE double-buffered staging ----------------------
// preload tile0; per step: ONE barrier, prefetch k+1 into other buf, compute k.
// C[M][ldc] tile = A[M][1024] * Bt[N][1024]^T ; optional fused L2-norm per 64-col head
// Q columns (n0<1024) additionally scaled by C1 = 8*log2(e) (softmax scale folding).
template <int WRITE_F32, int NORM>
__global__ __launch_bounds__(256) void gemm_tile(const bf16_t* __restrict__ A,
                                                 const bf16_t* __restrict__ Bt,
                                                 void* __restrict__ Cout, int ldc) {
    constexpr int K = D_MODEL;
    __shared__ __align__(16) bf16_t As[2][128 * 32];
    __shared__ __align__(16) bf16_t Bs[2][128 * 32];
    const int tid = threadIdx.x;
    const int m0 = blockIdx.y * 128;
    const int n0 = blockIdx.x * 128;
    const int wave = tid >> 6;
    const int lane = tid & 63;
    const int l15 = lane & 15;
    const int quad = lane >> 4;
    const int wm = (wave >> 1) * 64;
    const int wn = (wave & 1) * 64;
    f32x4 acc[4][4] = {};

    // staging: thread t handles chunks t and t+256; chunk c: row=c>>2, off=(c&3)*8
    const int srow = tid >> 2;
    const int soff = (tid & 3) * 8;
    const bf16_t* gA = A + (size_t)(m0 + srow) * K + soff;
    const bf16_t* gB = Bt + (size_t)(n0 + srow) * K + soff;
    constexpr int HGAP = 64 * K;

    // preload K-tile 0 into buf 0
    async_copy16(gA, &As[0][tid * 8]);
    async_copy16(gA + HGAP, &As[0][tid * 8 + 2048]);
    async_copy16(gB, &Bs[0][tid * 8]);
    async_copy16(gB + HGAP, &Bs[0][tid * 8 + 2048]);

    for (int kt = 0; kt < K; kt += 32) {
        const int b = (kt >> 5) & 1;
        __syncthreads();               // drains vmcnt: tile kt (buf b) landed; prior readers done
        if (kt + 32 < K) {             // prefetch tile kt+32 into the other buffer
            async_copy16(gA + kt + 32, &As[b ^ 1][tid * 8]);
            async_copy16(gA + HGAP + kt + 32, &As[b ^ 1][tid * 8 + 2048]);
            async_copy16(gB + kt + 32, &Bs[b ^ 1][tid * 8]);
            async_copy16(gB + HGAP + kt + 32, &Bs[b ^ 1][tid * 8 + 2048]);
        }
        bf16x8 af[4], bfr[4];
#pragma unroll
        for (int mi = 0; mi < 4; mi++)
            af[mi] = *(const bf16x8*)(&As[b][(wm + mi * 16 + l15) * 32 + quad * 8]);
#pragma unroll
        for (int ni = 0; ni < 4; ni++)
            bfr[ni] = *(const bf16x8*)(&Bs[b][(wn + ni * 16 + l15) * 32 + quad * 8]);
#pragma unroll
        for (int mi = 0; mi < 4; mi++)
#pragma unroll
            for (int ni = 0; ni < 4; ni++)
                acc[mi][ni] = __builtin_amdgcn_mfma_f32_16x16x32_bf16(
                    af[mi], bfr[ni], acc[mi][ni], 0, 0, 0);
    }

    if (NORM && n0 < 2048) {   // wave's 64-col span == one head: fused F.normalize
        const float post = (n0 < 1024) ? C1 : 1.0f;   // fold softmax scale into Q
#pragma unroll
        for (int mi = 0; mi < 4; mi++)
#pragma unroll
            for (int r = 0; r < 4; r++) {
                float s = 0.f;
#pragma unroll
                for (int ni = 0; ni < 4; ni++) {
                    float v = acc[mi][ni][r];
                    s += v * v;
                }
                s += __shfl_xor(s, 1);
                s += __shfl_xor(s, 2);
                s += __shfl_xor(s, 4);
                s += __shfl_xor(s, 8);
                float sc = post / fmaxf(sqrtf(s), 1e-12f);
#pragma unroll
                for (int ni = 0; ni < 4; ni++) acc[mi][ni][r] *= sc;
            }
    }
#pragma unroll
    for (int mi = 0; mi < 4; mi++)
#pragma unroll
        for (int ni = 0; ni < 4; ni++)
#pragma unroll
            for (int r = 0; r < 4; r++) {
                int row = m0 + wm + mi * 16 + quad * 4 + r;
                int col = n0 + wn + ni * 16 + l15;
                float v = acc[mi][ni][r];
                if (WRITE_F32)
                    ((float*)Cout)[(size_t)row * ldc + col] = v;
                else
                    ((bf16_t*)Cout)[(size_t)row * ldc + col] = (bf16_t)v;
            }
}

// ---- V (QKV cols 2048..3071) -> Vt[h][d][n], tokens in MFMA k-enum order ----------
// Within each 32-token tile, position kk holds token j(kk) = 16*((kk&7)>>2)
// + 4*(kk>>3) + (kk&3)  => PV A-fragment becomes ONE contiguous b128 LDS read.
__global__ __launch_bounds__(256) void transpose_v_kernel(const bf16_t* __restrict__ QKV,
                                                          bf16_t* __restrict__ Vt) {
    __shared__ bf16_t t[64][72];
    int n0 = blockIdx.x * 64;
    int h = blockIdx.y;
    int tx = threadIdx.x & 63, ty = threadIdx.x >> 6;
#pragma unroll
    for (int i = 0; i < 16; i++) {
        int nl = ty * 16 + i;
        t[nl][tx] = QKV[(size_t)(n0 + nl) * 3072 + 2048 + h * DH + tx];
    }
    __syncthreads();
    const int e = tx & 7, q = (tx >> 3) & 3;
    const int J = (tx & 32) + 16 * (e >> 2) + 4 * q + (e & 3);   // permuted token
#pragma unroll
    for (int i = 0; i < 16; i++) {
        int dl = ty * 16 + i;
        Vt[(size_t)(h * DH + dl) * N_TOK + n0 + tx] = t[J][dl];
    }
}

// ------- flash attention v20: v10 block mapping + v14 softmax cuts -----------------
// Trajectory bookkeeping: v10 (1024 blocks, ONE group per block, heavy-first)
// measured 63.6us; the balanced-pairing v12/v14 (512 blocks, two groups serially)
// measures 66.0-68.7us -- pairing re-runs the preload/drain prologue and halves
// resident blocks. v20 = v10 mapping (4 blocks/CU, natural backfill) + v14's body
// (softmax scale pre-folded into Q so p=exp2(sj); row-sum l via ones-MFMA).
__global__ __launch_bounds__(256) void attn_kernel(const bf16_t* __restrict__ QKV,
                                                   const bf16_t* __restrict__ Vt,
                                                   bf16_t* __restrict__ O) {
    __shared__ __align__(16) bf16_t Ks[2][4096];      // [buf][64 j x 64 d] chunk c@row = src c^(row&7)
    __shared__ __align__(16) bf16_t Vs[2][2][2048];   // [buf][half][64 d x 32 kk] chunk c@row d = src c^((d>>1)&3)
    const int tid = threadIdx.x;
    const int wave = tid >> 6;
    const int lane = tid & 63;
    const int l15 = lane & 15;
    const int quad = lane >> 4;

    const int xcd = blockIdx.x & 7;
    const int t = blockIdx.x >> 3;          // 0..127
    const int h = xcd * 2 + (t & 1);        // 2 heads per XCD
    const int g = 63 - (t >> 1);            // 64-row i-group, heaviest first
    const int i0 = g * 64 + wave * 16;      // this wave's 16 rows

    const bf16_t* Qb = QKV + h * DH;
    const bf16_t* Kb = QKV + 1024 + h * DH;
    const bf16_t* Vb = Vt + (size_t)h * DH * N_TOK;

    // Q^T B-fragment: lane n=l15 -> row i0+l15, k=quad*8.. contiguous
    bf16x8 aq[2];
#pragma unroll
    for (int kd = 0; kd < 2; kd++)
        aq[kd] = *(const bf16x8*)(Qb + (size_t)(i0 + l15) * 3072 + kd * 32 + quad * 8);

    f32x4 od[4] = {};          // O^T[d=mt*16+quad*4+r][i=l15]
    f32x4 lv = {};             // ones-MFMA row-sum accumulator (all rows equal)

    // staging: K chunk idx L=tid+256*i -> (row=(tid>>3)+32*i, c=tid&7), src c^(row&7)
    const int krow = tid >> 3;
    const int kc = (tid & 7) ^ (krow & 7);
    const bf16_t* gK = Kb + (size_t)krow * 3072 + kc * 8;
    // V chunk idx tid -> (d=tid>>2, c=tid&3), src chunk c^((d>>1)&3); two 32-kk halves
    const int vd = tid >> 2;
    const int vc = (tid & 3) ^ ((vd >> 1) & 3);
    const bf16_t* gV = Vb + (size_t)vd * N_TOK + vc * 8;

    // preload tile 0 into buf 0
    async_copy16(gK, &Ks[0][tid * 8]);
    async_copy16(gK + (size_t)32 * 3072, &Ks[0][tid * 8 + 2048]);
    async_copy16(gV, &Vs[0][0][tid * 8]);
    async_copy16(gV + 32, &Vs[0][1][tid * 8]);

    const int ksw = l15 & 7;             // K-tile read swizzle
    const int vsw = (l15 >> 1) & 3;      // V-tile read swizzle (16B chunks)

    // all-ones A-fragment for MFMA row-sums of P
    bf16x8 vone;
#pragma unroll
    for (int i = 0; i < 8; i++) vone[i] = (bf16_t)1.0f;

    for (int jt = 0; jt <= g; jt++) {
        __syncthreads();                 // drains vmcnt: buf[jt&1] ready; prior reads done
        if (jt < g) {                    // prefetch next tile into other buf
            const int b = (jt + 1) & 1;
            const bf16_t* kn = gK + (size_t)(jt + 1) * 64 * 3072;
            async_copy16(kn, &Ks[b][tid * 8]);
            async_copy16(kn + (size_t)32 * 3072, &Ks[b][tid * 8 + 2048]);
            async_copy16(gV + (jt + 1) * 64, &Vs[b][0][tid * 8]);
            async_copy16(gV + (jt + 1) * 64 + 32, &Vs[b][1][tid * 8]);
        }
        const bf16_t* KS = Ks[jt & 1];
        const bool diag = (jt == g);
        const int jh_max = diag ? wave : 3;

        // ---- S^T = K.Q^T over 4 jh sub-tiles (independent chains) ----
        bf16x8 ak[4][2];
#pragma unroll
        for (int jh = 0; jh < 4; jh++) {
            if (jh > jh_max) continue;
#pragma unroll
            for (int kd = 0; kd < 2; kd++)
                ak[jh][kd] = *(const bf16x8*)(&KS[(jh * 16 + l15) * 64 +
                                                  (((kd * 4 + quad) ^ ksw) * 8)]);
        }
        f32x4 sj[4] = {};
#pragma unroll
        for (int kd = 0; kd < 2; kd++)
#pragma unroll
            for (int jh = 0; jh < 4; jh++) {
                if (jh > jh_max) continue;
                sj[jh] = __builtin_amdgcn_mfma_f32_16x16x32_bf16(ak[jh][kd], aq[kd], sj[jh], 0, 0, 0);
            }

        // ---- softmax: p = exp2(sj) (scale pre-folded into Q, shift cancels) ----
        float p[4][4] = {};
#pragma unroll
        for (int jh = 0; jh < 4; jh++) {
            if (jh > jh_max) continue;
            if (diag && jh == wave) {
#pragma unroll
                for (int r = 0; r < 4; r++)
                    p[jh][r] = (quad * 4 + r > l15) ? 0.f
                               : __builtin_amdgcn_exp2f(sj[jh][r]);
            } else {
#pragma unroll
                for (int r = 0; r < 4; r++)
                    p[jh][r] = __builtin_amdgcn_exp2f(sj[jh][r]);
            }
        }
        // pack P^T B-fragments: half H covers jh = 2H, 2H+1 (k-enum j(q,e))
        bf16x8 pk8[2];
#pragma unroll
        for (int H = 0; H < 2; H++)
#pragma unroll
            for (int r = 0; r < 4; r++) {
                pk8[H][r] = (bf16_t)p[2 * H][r];
                pk8[H][4 + r] = (bf16_t)p[2 * H + 1][r];
            }

        // ---- l += ones.P^T (row-sums via matrix pipe; all output rows equal) ----
        lv = __builtin_amdgcn_mfma_f32_16x16x32_bf16(vone, pk8[0], lv, 0, 0, 0);
        if (jh_max >= 2)
            lv = __builtin_amdgcn_mfma_f32_16x16x32_bf16(vone, pk8[1], lv, 0, 0, 0);

        // ---- O^T += V^T.P^T : one b128 A-frag per (mt, half) ----
        const bf16_t* VS0 = Vs[jt & 1][0];
#pragma unroll
        for (int mt = 0; mt < 4; mt++) {
            bf16x8 vf = *(const bf16x8*)(&VS0[(mt * 16 + l15) * 32 + ((quad ^ vsw) * 8)]);
            od[mt] = __builtin_amdgcn_mfma_f32_16x16x32_bf16(vf, pk8[0], od[mt], 0, 0, 0);
        }
        if (jh_max >= 2) {
            const bf16_t* VS1 = Vs[jt & 1][1];
#pragma unroll
            for (int mt = 0; mt < 4; mt++) {
                bf16x8 vf = *(const bf16x8*)(&VS1[(mt * 16 + l15) * 32 + ((quad ^ vsw) * 8)]);
                od[mt] = __builtin_amdgcn_mfma_f32_16x16x32_bf16(vf, pk8[1], od[mt], 0, 0, 0);
            }
        }
    }

    // ---- normalize: lv[r] = full row-sum for col i=l15 (contraction spans lanes) ----
    float inv = 1.0f / lv[0];

#pragma unroll
    for (int mt = 0; mt < 4; mt++) {
        bf16x4 o;
#pragma unroll
        for (int r = 0; r < 4; r++) o[r] = (bf16_t)(od[mt][r] * inv);
        *(bf16x4*)(&O[(size_t)(i0 + l15) * D_MODEL + h * DH + mt * 16 + quad * 4]) = o;
    }
}

extern "C" void kernel_launch(void* const* d_in, const int* in_sizes, int n_in,
                              void* d_out, int out_size, void* d_ws, size_t ws_size,
                              hipStream_t stream) {
    const float* x  = (const float*)d_in[0];
    const float* Wq = (const float*)d_in[1];
    const float* Wk = (const float*)d_in[2];
    const float* Wv = (const float*)d_in[3];
    const float* Wo = (const float*)d_in[4];
    float* out = (float*)d_out;
    char* ws = (char*)d_ws;
    const size_t MB = 1024 * 1024;
    bf16_t* xb   = (bf16_t*)(ws);             // 8 MB
    bf16_t* Wt3  = (bf16_t*)(ws + 8 * MB);    // 6 MB  [3072][1024] q|k|v
    bf16_t* Wot  = (bf16_t*)(ws + 14 * MB);   // 2 MB
    bf16_t* QKV  = (bf16_t*)(ws + 16 * MB);   // 24 MB [4096][3072]
    bf16_t* Vt   = (bf16_t*)(ws + 40 * MB);   // 8 MB  [16][64][4096] (k-enum order)
    bf16_t* Ob   = (bf16_t*)(ws + 48 * MB);   // 8 MB  -> ends at 56 MB

    cast_x_kernel<<<4096, 256, 0, stream>>>(x, xb);
    dim3 gw(16, 16, 4);
    transpose_w_kernel<<<gw, 256, 0, stream>>>(Wq, Wk, Wv, Wo,
                                               Wt3, Wt3 + 1024 * 1024, Wt3 + 2 * 1024 * 1024, Wot);
    dim3 gqkv(3072 / 128, N_TOK / 128);
    gemm_tile<0, 1><<<gqkv, 256, 0, stream>>>(xb, Wt3, QKV, 3072);
    dim3 gv(N_TOK / 64, HEADS);
    transpose_v_kernel<<<gv, 256, 0, stream>>>(QKV, Vt);
    attn_kernel<<<1024, 256, 0, stream>>>(QKV, Vt, Ob);
    dim3 go(D_MODEL / 128, N_TOK / 128);
    gemm_tile<1, 0><<<go, 256, 0, stream>>>(Ob, Wot, out, D_MODEL);
}